// Round 5
// baseline (4881.187 us; speedup 1.0000x reference)
//
#include <hip/hip_runtime.h>
#include <math.h>

// ---------------- problem constants ----------------
#define BB     64
#define LLEN   197
#define LPAD   224        // padded sequence for kv contraction (7*32)
#define BLROWS 12608      // BB*LLEN
#define MPAD   12672      // BLROWS padded to 99*128 (also 198*64)
#define DMODEL 192
#define NHEAD  3
#define DHEAD  64
#define M2FEAT 256
#define FFDIM  768
#define NDEPTH 12
#define NCLS   1000
#define NPATCH 196
#define BPROWS 12544      // BB*NPATCH (= 196*64 exactly)
#define KPATCH 768

#define MODE_PLAIN 0
#define MODE_RELU  1
#define MODE_RES   2

typedef unsigned short ushort;
typedef __attribute__((ext_vector_type(8))) short bf16x8;
typedef __attribute__((ext_vector_type(4))) float floatx4;
typedef __attribute__((ext_vector_type(4))) short short4v;

__device__ __forceinline__ float wave_reduce_sum(float v) {
#pragma unroll
  for (int s = 32; s > 0; s >>= 1) v += __shfl_xor(v, s, 64);
  return v;
}
__device__ __forceinline__ ushort f2bf(float f) {  // RNE fp32->bf16
  unsigned u = __float_as_uint(f);
  return (ushort)((u + 0x7fffu + ((u >> 16) & 1u)) >> 16);
}
__device__ __forceinline__ float bf2f(ushort u) {
  return __uint_as_float(((unsigned)u) << 16);
}
// async global->LDS, 16 B per lane; LDS dest wave-uniform (HW adds lane*16)
__device__ __forceinline__ void gll16(const ushort* g, ushort* l) {
  __builtin_amdgcn_global_load_lds(
      (const __attribute__((address_space(1))) void*)g,
      (__attribute__((address_space(3))) void*)l, 16, 0, 0);
}
// wait vmcnt(0) only (expcnt=7, lgkmcnt=15 untouched)
__device__ __forceinline__ void wait_vm0() { __builtin_amdgcn_s_waitcnt(0x0f70); }

// =========== wave-split-K GEMM: C = A[M,K]@W[N,K]^T + bias (+relu/+res) ===========
// tile 64x64 per BLOCK; 4 waves round-robin over BK=32 K-chunks with PRIVATE LDS
// slots (no barriers in K-loop -> no block-wide vmcnt convoy); fp32 tree-reduce
// across waves through the dead staging LDS; epilogue split cols 0-31/32-63
// between waves 0/1.
__global__ __launch_bounds__(256) void gemm_ws(
    const ushort* __restrict__ A, int lda,
    const ushort* __restrict__ W, int ldw,
    const float* __restrict__ bias, const ushort* __restrict__ R,
    ushort* __restrict__ C, int ldc, int Mreal, int Ndim, int Kdim, int mode)
{
  __shared__ __align__(16) ushort S[4][4096];   // per-wave: A 64x32 | W 64x32
  const int tid = threadIdx.x;
  const int bm = blockIdx.x, bn = blockIdx.y;
  const int wave = tid >> 6, lane = tid & 63;
  const int quad = lane >> 4, l16 = lane & 15;
  const int lrow16 = lane >> 2, lq8 = (lane & 3) * 8;  // gll16: 16 rows / inst
  ushort* As = S[wave];
  ushort* Ws = S[wave] + 2048;
  const ushort* Ap = A + (size_t)(bm * 64) * lda;
  const ushort* Wp = W + (size_t)(bn * 64) * ldw;
  floatx4 acc[4][4] = {};
  const int nT = Kdim >> 5;
  for (int kt = wave; kt < nT; kt += 4) {
    const int kk = kt * 32;
#pragma unroll
    for (int g = 0; g < 4; ++g)
      gll16(Ap + (size_t)(g * 16 + lrow16) * lda + kk + lq8, As + g * 16 * 32);
#pragma unroll
    for (int g = 0; g < 4; ++g)
      gll16(Wp + (size_t)(g * 16 + lrow16) * ldw + kk + lq8, Ws + g * 16 * 32);
    wait_vm0();
    bf16x8 af[4], bf[4];
#pragma unroll
    for (int i = 0; i < 4; ++i) {
      af[i] = *(const bf16x8*)&As[(i * 16 + l16) * 32 + quad * 8];
      bf[i] = *(const bf16x8*)&Ws[(i * 16 + l16) * 32 + quad * 8];
    }
#pragma unroll
    for (int i = 0; i < 4; ++i)
#pragma unroll
      for (int j = 0; j < 4; ++j)
        acc[i][j] = __builtin_amdgcn_mfma_f32_16x16x32_bf16(af[i], bf[j], acc[i][j], 0, 0, 0);
  }
  // ---- cross-wave reduce: (0+2) and (1+3), then halves swap ----
  float* red = (float*)&S[0][0];     // 8192 floats = 2 x (64x64)
  __syncthreads();
  if (wave >= 2) {
    float* dst = red + (wave - 2) * 4096;
#pragma unroll
    for (int i = 0; i < 4; ++i)
#pragma unroll
      for (int j = 0; j < 4; ++j)
#pragma unroll
        for (int r = 0; r < 4; ++r)
          dst[(i * 16 + quad * 4 + r) * 64 + j * 16 + l16] = acc[i][j][r];
  }
  __syncthreads();
  if (wave < 2) {
    const float* src = red + wave * 4096;
#pragma unroll
    for (int i = 0; i < 4; ++i)
#pragma unroll
      for (int j = 0; j < 4; ++j)
#pragma unroll
        for (int r = 0; r < 4; ++r)
          acc[i][j][r] += src[(i * 16 + quad * 4 + r) * 64 + j * 16 + l16];
  }
  __syncthreads();
  // round 2: w1 gives cols 0-31 to w0; w0 gives cols 32-63 to w1
  if (wave == 1) {
#pragma unroll
    for (int i = 0; i < 4; ++i)
#pragma unroll
      for (int j = 0; j < 2; ++j)
#pragma unroll
        for (int r = 0; r < 4; ++r)
          red[(i * 16 + quad * 4 + r) * 32 + j * 16 + l16] = acc[i][j][r];
  } else if (wave == 0) {
#pragma unroll
    for (int i = 0; i < 4; ++i)
#pragma unroll
      for (int j = 2; j < 4; ++j)
#pragma unroll
        for (int r = 0; r < 4; ++r)
          red[2048 + (i * 16 + quad * 4 + r) * 32 + (j - 2) * 16 + l16] = acc[i][j][r];
  }
  __syncthreads();
  if (wave < 2) {
    const int j0 = wave * 2;
#pragma unroll
    for (int jj = 0; jj < 2; ++jj) {
      const int j = j0 + jj;
#pragma unroll
      for (int i = 0; i < 4; ++i)
#pragma unroll
        for (int r = 0; r < 4; ++r)
          acc[i][j][r] += red[(size_t)wave * 2048 +
                              (i * 16 + quad * 4 + r) * 32 + jj * 16 + l16];
    }
    // epilogue
#pragma unroll
    for (int jj = 0; jj < 2; ++jj) {
      const int j = j0 + jj;
      const int col = bn * 64 + j * 16 + l16;
      const float bv = bias[col];
#pragma unroll
      for (int i = 0; i < 4; ++i) {
#pragma unroll
        for (int r = 0; r < 4; ++r) {
          const int grow = bm * 64 + i * 16 + quad * 4 + r;
          if (grow >= Mreal) continue;
          float o = acc[i][j][r] + bv;
          if (mode == MODE_RELU) o = fmaxf(o, 0.f);
          else if (mode == MODE_RES) o += bf2f(R[(size_t)grow * ldc + col]);
          C[(size_t)grow * ldc + col] = f2bf(o);
        }
      }
    }
  }
}

// =========== FAVOR via MFMA (one-shot K=64) ===========
// grid (2 l-tiles, 192 bh, 2 q/k). phiQ [bh][l 224][m 256]; phiKt [bh][m 256][l 224]
__global__ __launch_bounds__(256) void favor_gemm(
    const ushort* __restrict__ qkv, const ushort* __restrict__ OmT,
    ushort* __restrict__ PhiQ, ushort* __restrict__ PhiKt)
{
  __shared__ __align__(16) ushort As[128 * 64];
  __shared__ __align__(16) ushort Bs[128 * 64];
  __shared__ float offs[128];
  const int tid = threadIdx.x;
  const int bx = blockIdx.x, bh = blockIdx.y, zz = blockIdx.z;
  const int b = bh / 3, h = bh - b * 3;
  const int zoff = zz ? 192 : 0;
  const int wave = tid >> 6, lane = tid & 63;
  const int wm = (wave >> 1) * 64, wn = (wave & 1) * 64;
  const int quad = lane >> 4, l16 = lane & 15;
  const int lrow8 = lane >> 3, lk8 = (lane & 7) * 8;
#pragma unroll
  for (int t = 0; t < 4; ++t) {
    const int rb = (t * 4 + wave) * 8;    // 8-row group (128B rows)
    const int l = bx * 128 + rb + lrow8;
    gll16(qkv + (size_t)(b * 197 + l) * 576 + zoff + h * 64 + lk8, &As[rb * 64]);
    gll16(OmT + (size_t)(rb + lrow8) * 64 + lk8, &Bs[rb * 64]);
  }
  __syncthreads();
  {
    const int row = tid >> 1, half = tid & 1;
    float s = 0.f;
#pragma unroll
    for (int t = 0; t < 4; ++t) {
      bf16x8 v8 = *(const bf16x8*)&As[row * 64 + half * 32 + t * 8];
#pragma unroll
      for (int q = 0; q < 8; ++q) { float xv = bf2f((ushort)v8[q]); s += xv * xv; }
    }
    s += __shfl_xor(s, 1, 64);
    if (half == 0) offs[row] = 0.0625f * s;   // 0.5*scale^2 (scale^2 = 0.125)
  }
  floatx4 acc[4][4] = {};
#pragma unroll
  for (int ks = 0; ks < 64; ks += 32) {
    bf16x8 af[4], bf[4];
#pragma unroll
    for (int i = 0; i < 4; ++i) {
      af[i] = *(const bf16x8*)&As[(wm + i * 16 + l16) * 64 + ks + (quad * 8)];
      bf[i] = *(const bf16x8*)&Bs[(wn + i * 16 + l16) * 64 + ks + (quad * 8)];
    }
#pragma unroll
    for (int i = 0; i < 4; ++i)
#pragma unroll
      for (int j = 0; j < 4; ++j)
        acc[i][j] = __builtin_amdgcn_mfma_f32_16x16x32_bf16(af[i], bf[j], acc[i][j], 0, 0, 0);
  }
  __syncthreads();
  if (zz == 0) {
#pragma unroll
    for (int i = 0; i < 4; ++i) {
      const int ll0 = wm + i * 16 + quad * 4;
#pragma unroll
      for (int r = 0; r < 4; ++r) {
        const int l = bx * 128 + ll0 + r;
        if (l >= 197) continue;
        const float off = offs[ll0 + r];
#pragma unroll
        for (int j = 0; j < 4; ++j) {
          const int m = wn + j * 16 + l16;
          const float u = acc[i][j][r];
          ushort* p = PhiQ + ((size_t)bh * 224 + l) * 256 + m;
          p[0]   = f2bf(__expf(u - off)  * 0.0625f);
          p[128] = f2bf(__expf(-u - off) * 0.0625f);
        }
      }
    }
  } else {
    // transposed layout: r-index maps to consecutive l -> short4 stores
#pragma unroll
    for (int i = 0; i < 4; ++i) {
      const int ll0 = wm + i * 16 + quad * 4;
      const int l0 = bx * 128 + ll0;
#pragma unroll
      for (int j = 0; j < 4; ++j) {
        const int m = wn + j * 16 + l16;
        short4v ep, em;
#pragma unroll
        for (int r = 0; r < 4; ++r) {
          const float off = offs[ll0 + r];
          const float u = acc[i][j][r];
          ep[r] = (short)f2bf(__expf(u - off)  * 0.0625f);
          em[r] = (short)f2bf(__expf(-u - off) * 0.0625f);
        }
        if (l0 + 3 < 197) {
          *(short4v*)(PhiKt + ((size_t)bh * 256 + m) * 224 + l0) = ep;
          *(short4v*)(PhiKt + ((size_t)bh * 256 + m + 128) * 224 + l0) = em;
        } else {
#pragma unroll
          for (int r = 0; r < 4; ++r) {
            if (l0 + r < 197) {
              PhiKt[((size_t)bh * 256 + m) * 224 + l0 + r] = (ushort)ep[r];
              PhiKt[((size_t)bh * 256 + m + 128) * 224 + l0 + r] = (ushort)em[r];
            }
          }
        }
      }
    }
  }
}

// =========== V transpose: Vt[bh][80][224] = [V^T ; ones ; zeros] ===========
__global__ __launch_bounds__(256) void v_transpose(
    const ushort* __restrict__ qkv, ushort* __restrict__ Vt)
{
  __shared__ ushort t[64][65];
  const int bh = blockIdx.x;
  const int b = bh / 3, h = bh - b * 3;
  const int tid = threadIdx.x;
  for (int lt = 0; lt < 4; ++lt) {
    __syncthreads();
    for (int e = tid; e < 4096; e += 256) {
      const int ll = e >> 6, d = e & 63;
      const int l = lt * 64 + ll;
      ushort v = 0;
      if (l < 197) v = qkv[(size_t)(b * 197 + l) * 576 + 384 + h * 64 + d];
      t[d][ll] = v;
    }
    __syncthreads();
    for (int e = tid; e < 4096; e += 256) {
      const int d = e >> 6, ll = e & 63;
      const int l = lt * 64 + ll;
      if (l < 224) Vt[((size_t)bh * 80 + d) * 224 + l] = t[d][ll];
    }
  }
  for (int d = 64; d < 80; ++d)
    for (int l = tid; l < 224; l += 256)
      Vt[((size_t)bh * 80 + d) * 224 + l] = (d == 64 && l < 197) ? 0x3F80 : 0;
}

// =========== KV = phiK^T @ [V | 1 | 0], double-buffered ===========
// grid (192 bh, 2 mhalf): M=128 feats, N=80, K=224. out KVt [bh][80][256]
__global__ __launch_bounds__(256) void kv_gemm(
    const ushort* __restrict__ PhiKt, const ushort* __restrict__ Vt,
    ushort* __restrict__ KVt)
{
  __shared__ __align__(16) ushort As[2][128 * 32];
  __shared__ __align__(16) ushort Bs[2][80 * 32];
  const int tid = threadIdx.x;
  const int bh = blockIdx.x, mhalf = blockIdx.y;
  const int wave = tid >> 6, lane = tid & 63;
  const int quad = lane >> 4, l16 = lane & 15;
  const int lrow = lane >> 2, lk = (lane & 3) * 8;
  const ushort* Ap = PhiKt + ((size_t)bh * 256 + mhalf * 128) * 224;
  const ushort* Bp = Vt + (size_t)bh * 80 * 224;
  floatx4 acc[2][5] = {};
#pragma unroll
  for (int t = 0; t < 2; ++t) {
    const int rb = (t * 4 + wave) * 16;
    gll16(Ap + (size_t)(rb + lrow) * 224 + lk, &As[0][rb * 32]);
  }
  gll16(Bp + (size_t)(wave * 16 + lrow) * 224 + lk, &Bs[0][wave * 16 * 32]);
  if (wave == 0) gll16(Bp + (size_t)(64 + lrow) * 224 + lk, &Bs[0][64 * 32]);
  for (int c = 0; c < 7; ++c) {
    const int cur = c & 1;
    __syncthreads();
    if (c + 1 < 7) {
      const int l0 = (c + 1) * 32, nxt = cur ^ 1;
#pragma unroll
      for (int t = 0; t < 2; ++t) {
        const int rb = (t * 4 + wave) * 16;
        gll16(Ap + (size_t)(rb + lrow) * 224 + l0 + lk, &As[nxt][rb * 32]);
      }
      gll16(Bp + (size_t)(wave * 16 + lrow) * 224 + l0 + lk, &Bs[nxt][wave * 16 * 32]);
      if (wave == 0) gll16(Bp + (size_t)(64 + lrow) * 224 + l0 + lk, &Bs[nxt][64 * 32]);
    }
    bf16x8 af[2], bf[5];
#pragma unroll
    for (int i = 0; i < 2; ++i)
      af[i] = *(const bf16x8*)&As[cur][(wave * 32 + i * 16 + l16) * 32 + quad * 8];
#pragma unroll
    for (int j = 0; j < 5; ++j)
      bf[j] = *(const bf16x8*)&Bs[cur][(j * 16 + l16) * 32 + quad * 8];
#pragma unroll
    for (int i = 0; i < 2; ++i)
#pragma unroll
      for (int j = 0; j < 5; ++j)
        acc[i][j] = __builtin_amdgcn_mfma_f32_16x16x32_bf16(af[i], bf[j], acc[i][j], 0, 0, 0);
  }
#pragma unroll
  for (int i = 0; i < 2; ++i) {
    const int m0 = mhalf * 128 + wave * 32 + i * 16 + quad * 4;
#pragma unroll
    for (int j = 0; j < 5; ++j) {
      const int d = j * 16 + l16;
      short4v pk;
#pragma unroll
      for (int r = 0; r < 4; ++r) pk[r] = (short)f2bf(acc[i][j][r]);
      *(short4v*)(KVt + ((size_t)bh * 80 + d) * 256 + m0) = pk;
    }
  }
}

// =========== attn: out = Z * (phiQ @ KVt^T), double-buffered ===========
// grid (2 l-tiles, 192 bh); block 256 = 4 waves of 32x80
__global__ __launch_bounds__(256) void attn_gemm(
    const ushort* __restrict__ PhiQ, const ushort* __restrict__ KVt,
    ushort* __restrict__ OUT)
{
  __shared__ __align__(16) ushort As[2][128 * 32];
  __shared__ __align__(16) ushort Bs[2][80 * 32];
  __shared__ float zs[128];
  const int tid = threadIdx.x;
  const int bx = blockIdx.x, bh = blockIdx.y;
  const int b = bh / 3, h = bh - b * 3;
  const int wave = tid >> 6, lane = tid & 63;
  const int quad = lane >> 4, l16 = lane & 15;
  const int lrow = lane >> 2, lk = (lane & 3) * 8;
  const ushort* Ap = PhiQ + ((size_t)bh * 224 + bx * 128) * 256;
  const ushort* Bp = KVt + (size_t)bh * 80 * 256;
  floatx4 acc[2][5] = {};
#pragma unroll
  for (int t = 0; t < 2; ++t) {
    const int rb = (t * 4 + wave) * 16;
    gll16(Ap + (size_t)(rb + lrow) * 256 + lk, &As[0][rb * 32]);
  }
  gll16(Bp + (size_t)(wave * 16 + lrow) * 256 + lk, &Bs[0][wave * 16 * 32]);
  if (wave == 0) gll16(Bp + (size_t)(64 + lrow) * 256 + lk, &Bs[0][64 * 32]);
  for (int c = 0; c < 8; ++c) {
    const int cur = c & 1;
    __syncthreads();
    if (c + 1 < 8) {
      const int m0 = (c + 1) * 32, nxt = cur ^ 1;
#pragma unroll
      for (int t = 0; t < 2; ++t) {
        const int rb = (t * 4 + wave) * 16;
        gll16(Ap + (size_t)(rb + lrow) * 256 + m0 + lk, &As[nxt][rb * 32]);
      }
      gll16(Bp + (size_t)(wave * 16 + lrow) * 256 + m0 + lk, &Bs[nxt][wave * 16 * 32]);
      if (wave == 0) gll16(Bp + (size_t)(64 + lrow) * 256 + m0 + lk, &Bs[nxt][64 * 32]);
    }
    bf16x8 af[2], bf[5];
#pragma unroll
    for (int i = 0; i < 2; ++i)
      af[i] = *(const bf16x8*)&As[cur][(wave * 32 + i * 16 + l16) * 32 + quad * 8];
#pragma unroll
    for (int j = 0; j < 5; ++j)
      bf[j] = *(const bf16x8*)&Bs[cur][(j * 16 + l16) * 32 + quad * 8];
#pragma unroll
    for (int i = 0; i < 2; ++i)
#pragma unroll
      for (int j = 0; j < 5; ++j)
        acc[i][j] = __builtin_amdgcn_mfma_f32_16x16x32_bf16(af[i], bf[j], acc[i][j], 0, 0, 0);
  }
  if (l16 == 0) {
#pragma unroll
    for (int i = 0; i < 2; ++i)
#pragma unroll
      for (int r = 0; r < 4; ++r)
        zs[wave * 32 + i * 16 + quad * 4 + r] = acc[i][4][r];
  }
  __syncthreads();
#pragma unroll
  for (int i = 0; i < 2; ++i) {
#pragma unroll
    for (int r = 0; r < 4; ++r) {
      const int ll = wave * 32 + i * 16 + quad * 4 + r;
      const int l = bx * 128 + ll;
      if (l >= 197) continue;
      const float z = 1.f / (zs[ll] + 1e-6f);
#pragma unroll
      for (int j = 0; j < 4; ++j)
        OUT[(size_t)(b * 197 + l) * 192 + h * 64 + j * 16 + l16] =
            f2bf(acc[i][j][r] * z);
    }
  }
}

// ---------------- weight pre-conversion ----------------
__global__ void conv_qkv(const float* __restrict__ Wq, const float* __restrict__ Wk,
                         const float* __restrict__ Wv, const float* __restrict__ bq,
                         const float* __restrict__ bk, const float* __restrict__ bv,
                         ushort* __restrict__ dst, float* __restrict__ bdst) {
  const int l = blockIdx.y;
  const int e = blockIdx.x * 256 + threadIdx.x;   // < 576*192
  const int n = e / 192, k = e - n * 192;
  const float* src;
  if (n < 192)      src = Wq + (size_t)l * 36864 + n * 192;
  else if (n < 384) src = Wk + (size_t)l * 36864 + (n - 192) * 192;
  else              src = Wv + (size_t)l * 36864 + (n - 384) * 192;
  dst[(size_t)l * 640 * 192 + e] = f2bf(src[k]);
  if (e < 576) {
    float bvv;
    if (e < 192)      bvv = bq[l * 192 + e];
    else if (e < 384) bvv = bk[l * 192 + e - 192];
    else              bvv = bv[l * 192 + e - 384];
    bdst[l * 576 + e] = bvv;
  }
}

__global__ void conv_pad(const float* __restrict__ src, ushort* __restrict__ dst,
                         int NK, int padNK) {
  const int l = blockIdx.y;
  const int e = blockIdx.x * 256 + threadIdx.x;
  if (e < NK) dst[(size_t)l * padNK + e] = f2bf(src[(size_t)l * NK + e]);
}

// omega [l][64 d][128 m] -> OmT' [l][128 m][64 d] * sqrt(temp)
__global__ void conv_omt(const float* __restrict__ om, ushort* __restrict__ dst) {
  const int l = blockIdx.y;
  const int e = blockIdx.x * 256 + threadIdx.x;   // < 8192
  const int m = e >> 6, d = e & 63;
  dst[(size_t)l * 8192 + e] = f2bf(0.35355339059327379f * om[(size_t)l * 8192 + d * 128 + m]);
}

__global__ void zero_phikt(ushort* __restrict__ PhiKt) {
  const int bh = blockIdx.x, m = threadIdx.x;
  ushort* p = PhiKt + ((size_t)bh * 256 + m) * 224;
  for (int l = 197; l < 224; ++l) p[l] = 0;
}

// ---------------- im2col (fp32 in -> bf16 out) ----------------
__global__ __launch_bounds__(256) void im2col_kernel(
    const float* __restrict__ X, ushort* __restrict__ Apd)
{
  const int bp = blockIdx.x;
  const int b = bp / NPATCH, p = bp - b * NPATCH;
  const int gh = p / 14, gw = p - gh * 14;
  for (int e = threadIdx.x; e < KPATCH; e += 256) {
    const int c = e >> 8, rem = e & 255, ph = rem >> 4, pw = rem & 15;
    Apd[(size_t)bp * KPATCH + e] =
        f2bf(X[((size_t)(b * 3 + c) * 224 + gh * 16 + ph) * 224 + gw * 16 + pw]);
  }
}

// ---------------- assemble tokens ----------------
__global__ __launch_bounds__(256) void assemble_kernel(
    const ushort* __restrict__ TK, const float* __restrict__ g,
    const float* __restrict__ bt, const float* __restrict__ cls,
    const float* __restrict__ pos, ushort* __restrict__ XC)
{
  const int w = threadIdx.x >> 6, lane = threadIdx.x & 63;
  const int row = blockIdx.x * 4 + w;
  const int b = row / LLEN, l = row - b * LLEN;
  float o0, o1, o2;
  if (l == 0) {
    o0 = cls[lane]; o1 = cls[lane + 64]; o2 = cls[lane + 128];
  } else {
    const ushort* tp = TK + (size_t)(b * NPATCH + l - 1) * DMODEL;
    const float x0 = bf2f(tp[lane]), x1 = bf2f(tp[lane + 64]), x2 = bf2f(tp[lane + 128]);
    const float s  = wave_reduce_sum(x0 + x1 + x2);
    const float sq = wave_reduce_sum(x0 * x0 + x1 * x1 + x2 * x2);
    const float mu = s * (1.f / 192.f);
    const float var = sq * (1.f / 192.f) - mu * mu;
    const float rs = rsqrtf(var + 1e-5f);
    o0 = (x0 - mu) * rs * g[lane]       + bt[lane];
    o1 = (x1 - mu) * rs * g[lane + 64]  + bt[lane + 64];
    o2 = (x2 - mu) * rs * g[lane + 128] + bt[lane + 128];
  }
  o0 += pos[l * DMODEL + lane];
  o1 += pos[l * DMODEL + lane + 64];
  o2 += pos[l * DMODEL + lane + 128];
  ushort* xp = XC + (size_t)row * DMODEL;
  xp[lane] = f2bf(o0); xp[lane + 64] = f2bf(o1); xp[lane + 128] = f2bf(o2);
}

// ---------------- LayerNorm (bf16 io) ----------------
__global__ __launch_bounds__(256) void ln_kernel(
    const ushort* __restrict__ Xin, ushort* __restrict__ Xout,
    const float* __restrict__ g, const float* __restrict__ bt)
{
  const int w = threadIdx.x >> 6, lane = threadIdx.x & 63;
  const int row = blockIdx.x * 4 + w;
  const ushort* xp = Xin + (size_t)row * DMODEL;
  const float x0 = bf2f(xp[lane]), x1 = bf2f(xp[lane + 64]), x2 = bf2f(xp[lane + 128]);
  const float s  = wave_reduce_sum(x0 + x1 + x2);
  const float sq = wave_reduce_sum(x0 * x0 + x1 * x1 + x2 * x2);
  const float mu = s * (1.f / 192.f);
  const float var = sq * (1.f / 192.f) - mu * mu;
  const float rs = rsqrtf(var + 1e-5f);
  ushort* op = Xout + (size_t)row * DMODEL;
  op[lane]       = f2bf((x0 - mu) * rs * g[lane]       + bt[lane]);
  op[lane + 64]  = f2bf((x1 - mu) * rs * g[lane + 64]  + bt[lane + 64]);
  op[lane + 128] = f2bf((x2 - mu) * rs * g[lane + 128] + bt[lane + 128]);
}

__global__ __launch_bounds__(256) void ln2_kernel(
    const ushort* __restrict__ Xin, ushort* __restrict__ Xout,
    const float* __restrict__ ga, const float* __restrict__ ba,
    const float* __restrict__ gb, const float* __restrict__ bb)
{
  const int w = threadIdx.x >> 6, lane = threadIdx.x & 63;
  const int row = blockIdx.x * 4 + w;
  const ushort* xp = Xin + (size_t)row * DMODEL;
  float x0 = bf2f(xp[lane]), x1 = bf2f(xp[lane + 64]), x2 = bf2f(xp[lane + 128]);
  {
    const float s  = wave_reduce_sum(x0 + x1 + x2);
    const float sq = wave_reduce_sum(x0 * x0 + x1 * x1 + x2 * x2);
    const float mu = s * (1.f / 192.f);
    const float var = sq * (1.f / 192.f) - mu * mu;
    const float rs = rsqrtf(var + 1e-5f);
    x0 = (x0 - mu) * rs * ga[lane]       + ba[lane];
    x1 = (x1 - mu) * rs * ga[lane + 64]  + ba[lane + 64];
    x2 = (x2 - mu) * rs * ga[lane + 128] + ba[lane + 128];
  }
  const float s  = wave_reduce_sum(x0 + x1 + x2);
  const float sq = wave_reduce_sum(x0 * x0 + x1 * x1 + x2 * x2);
  const float mu = s * (1.f / 192.f);
  const float var = sq * (1.f / 192.f) - mu * mu;
  const float rs = rsqrtf(var + 1e-5f);
  ushort* op = Xout + (size_t)row * DMODEL;
  op[lane]       = f2bf((x0 - mu) * rs * gb[lane]       + bb[lane]);
  op[lane + 64]  = f2bf((x1 - mu) * rs * gb[lane + 64]  + bb[lane + 64]);
  op[lane + 128] = f2bf((x2 - mu) * rs * gb[lane + 128] + bb[lane + 128]);
}

// ---------------- pool + head ----------------
__global__ __launch_bounds__(192) void pool_kernel(
    const ushort* __restrict__ XC, float* __restrict__ Zp)
{
  const int b = blockIdx.x, d = threadIdx.x;
  float s = 0.f;
#pragma unroll 4
  for (int l = 0; l < LLEN; ++l) s += bf2f(XC[(size_t)(b * LLEN + l) * DMODEL + d]);
  Zp[b * DMODEL + d] = s * (1.f / 197.f);
}

__global__ __launch_bounds__(256) void head_kernel(
    const float* __restrict__ Zp, const float* __restrict__ HW,
    const float* __restrict__ HB, float* __restrict__ OUTp)
{
  const int n = blockIdx.x * 256 + threadIdx.x;
  const int b = blockIdx.y;
  if (n < NCLS) {
    const float* z = Zp + b * DMODEL;
    const float* w = HW + (size_t)n * DMODEL;
    float s = HB[n];
#pragma unroll 4
    for (int d = 0; d < DMODEL; ++d) s = fmaf(z[d], w[d], s);
    OUTp[(size_t)b * NCLS + n] = s;
  }
}

// ---------------- host orchestration ----------------
extern "C" void kernel_launch(void* const* d_in, const int* in_sizes, int n_in,
                              void* d_out, int out_size, void* d_ws, size_t ws_size,
                              hipStream_t stream) {
  const float* x        = (const float*)d_in[0];
  const float* patch_w  = (const float*)d_in[1];
  const float* patch_b  = (const float*)d_in[2];
  const float* pe_ln_g  = (const float*)d_in[3];
  const float* pe_ln_b  = (const float*)d_in[4];
  const float* cls_tok  = (const float*)d_in[5];
  const float* pos_emb  = (const float*)d_in[6];
  const float* Wq = (const float*)d_in[7];
  const float* bq = (const float*)d_in[8];
  const float* Wk = (const float*)d_in[9];
  const float* bk = (const float*)d_in[10];
  const float* Wv = (const float*)d_in[11];
  const float* bv = (const float*)d_in[12];
  const float* Wo = (const float*)d_in[13];
  const float* bo = (const float*)d_in[14];
  const float* ln1_g = (const float*)d_in[15];
  const float* ln1_b = (const float*)d_in[16];
  const float* ln2_g = (const float*)d_in[17];
  const float* ln2_b = (const float*)d_in[18];
  const float* lnb_g = (const float*)d_in[19];
  const float* lnb_b = (const float*)d_in[20];
  const float* W1 = (const float*)d_in[21];
  const float* b1 = (const float*)d_in[22];
  const float* W2 = (const float*)d_in[23];
  const float* b2 = (const float*)d_in[24];
  const float* omega  = (const float*)d_in[25];
  const float* head_w = (const float*)d_in[26];
  const float* head_b = (const float*)d_in[27];
  float* out = (float*)d_out;
  char* wsb = (char*)d_ws;

  size_t off = 0;
  auto carve = [&](size_t bytes) { size_t o = off; off += (bytes + 255) & ~(size_t)255; return o; };
  ushort* xc     = (ushort*)(wsb + carve((size_t)MPAD * 192 * 2));
  ushort* qkv    = (ushort*)(wsb + carve((size_t)MPAD * 576 * 2));
  ushort* ab     = (ushort*)(wsb + carve((size_t)MPAD * 192 * 2));
  ushort* hidden = (ushort*)(wsb + carve((size_t)MPAD * 768 * 2));   // aliases im2col
  ushort* phiQ   = (ushort*)(wsb + carve(((size_t)192 * 224 + 256) * 256 * 2));
  ushort* phiKt  = (ushort*)(wsb + carve(((size_t)192 * 256 * 224 + 32768) * 2));
  ushort* Vt     = (ushort*)(wsb + carve((size_t)192 * 80 * 224 * 2));
  ushort* KVt    = (ushort*)(wsb + carve((size_t)192 * 80 * 256 * 2));
  float*  ZPb    = (float*)(wsb + carve((size_t)64 * 192 * 4));
  float*  bqkv   = (float*)(wsb + carve((size_t)12 * 576 * 4));
  ushort* Wqkv_bf = (ushort*)(wsb + carve((size_t)12 * 640 * 192 * 2));
  ushort* Wo_bf   = (ushort*)(wsb + carve((size_t)12 * 256 * 192 * 2));
  ushort* W1_bf   = (ushort*)(wsb + carve((size_t)12 * 768 * 192 * 2));
  ushort* W2_bf   = (ushort*)(wsb + carve((size_t)12 * 256 * 768 * 2));
  ushort* Wp_bf   = (ushort*)(wsb + carve((size_t)256 * 768 * 2));
  ushort* Om_bf   = (ushort*)(wsb + carve((size_t)12 * 128 * 64 * 2));
  ushort* i2c     = hidden;   // patch GEMM consumes before FF uses hidden

  // ---- pre-conversion ----
  conv_qkv<<<dim3(432, 12), 256, 0, stream>>>(Wq, Wk, Wv, bq, bk, bv, Wqkv_bf, bqkv);
  conv_pad<<<dim3(144, 12), 256, 0, stream>>>(Wo, Wo_bf, 36864, 256 * 192);
  conv_pad<<<dim3(576, 12), 256, 0, stream>>>(W1, W1_bf, 147456, 768 * 192);
  conv_pad<<<dim3(576, 12), 256, 0, stream>>>(W2, W2_bf, 147456, 256 * 768);
  conv_pad<<<dim3(576, 1), 256, 0, stream>>>(patch_w, Wp_bf, 147456, 256 * 768);
  conv_omt<<<dim3(32, 12), 256, 0, stream>>>(omega, Om_bf);
  zero_phikt<<<192, 256, 0, stream>>>(phiKt);

  // ---- patch embedding ----
  im2col_kernel<<<BPROWS, 256, 0, stream>>>(x, i2c);
  gemm_ws<<<dim3(BPROWS / 64, 3), 256, 0, stream>>>(i2c, KPATCH, Wp_bf, KPATCH,
      patch_b, nullptr, ab, DMODEL, BPROWS, DMODEL, KPATCH, MODE_PLAIN);
  assemble_kernel<<<BLROWS / 4, 256, 0, stream>>>(ab, pe_ln_g, pe_ln_b,
                                                  cls_tok, pos_emb, xc);

  const int exits[3] = {3, 7, 11};
  for (int i = 0; i < NDEPTH; ++i) {
    gemm_ws<<<dim3(MPAD / 64, 9), 256, 0, stream>>>(xc, DMODEL,
        Wqkv_bf + (size_t)i * 640 * 192, DMODEL, bqkv + i * 576, nullptr,
        qkv, 576, BLROWS, 576, DMODEL, MODE_PLAIN);
    favor_gemm<<<dim3(2, 192, 2), 256, 0, stream>>>(qkv,
        Om_bf + (size_t)i * 8192, phiQ, phiKt);
    v_transpose<<<192, 256, 0, stream>>>(qkv, Vt);
    kv_gemm<<<dim3(192, 2), 256, 0, stream>>>(phiKt, Vt, KVt);
    attn_gemm<<<dim3(2, 192), 256, 0, stream>>>(phiQ, KVt, ab);
    gemm_ws<<<dim3(MPAD / 64, 3), 256, 0, stream>>>(ab, DMODEL,
        Wo_bf + (size_t)i * 256 * 192, DMODEL, bo + i * DMODEL, xc,
        xc, DMODEL, BLROWS, DMODEL, DMODEL, MODE_RES);
    ln_kernel<<<BLROWS / 4, 256, 0, stream>>>(xc, xc, ln1_g + i * DMODEL,
                                              ln1_b + i * DMODEL);
    gemm_ws<<<dim3(MPAD / 64, 12), 256, 0, stream>>>(xc, DMODEL,
        W1_bf + (size_t)i * 768 * 192, DMODEL, b1 + i * FFDIM, nullptr,
        hidden, FFDIM, BLROWS, FFDIM, DMODEL, MODE_RELU);
    gemm_ws<<<dim3(MPAD / 64, 3), 256, 0, stream>>>(hidden, FFDIM,
        W2_bf + (size_t)i * 256 * 768, FFDIM, b2 + i * DMODEL, xc,
        ab, DMODEL, BLROWS, DMODEL, FFDIM, MODE_RES);
    ln2_kernel<<<BLROWS / 4, 256, 0, stream>>>(ab, xc,
        ln2_g + i * DMODEL, ln2_b + i * DMODEL,
        lnb_g + i * DMODEL, lnb_b + i * DMODEL);

    for (int j = 0; j < 3; ++j) {
      if (i == exits[j]) {
        pool_kernel<<<BB, 192, 0, stream>>>(xc, ZPb);
        head_kernel<<<dim3(4, BB), 256, 0, stream>>>(
            ZPb, head_w + (size_t)j * NCLS * DMODEL, head_b + (size_t)j * NCLS,
            out + (size_t)j * BB * NCLS);
      }
    }
  }
}